// Round 1
// baseline (946.018 us; speedup 1.0000x reference)
//
#include <hip/hip_runtime.h>
#include <hip/hip_bf16.h>
#include <math.h>

#define B_   4
#define S_   2048
#define H_   1024
#define F_   3584
#define E_   8
#define TOPK 2
#define CAP  640
#define M_   (B_*CAP)    // 2560 rows per expert (b*CAP + c)
#define NTOK (B_*S_)     // 8192

typedef __attribute__((ext_vector_type(8))) short short8;
typedef __attribute__((ext_vector_type(4))) float f32x4;
typedef __attribute__((ext_vector_type(4))) unsigned short us4;

static __device__ __forceinline__ unsigned short f2bf(float f) {
  __hip_bfloat16 h = __float2bfloat16(f);
  return *reinterpret_cast<unsigned short*>(&h);
}
static __device__ __forceinline__ float bf2f(unsigned short u) {
  unsigned int x = ((unsigned int)u) << 16;
  float f;
  __builtin_memcpy(&f, &x, 4);
  return f;
}

static __device__ __forceinline__ void gload16(const void* g, void* l) {
  __builtin_amdgcn_global_load_lds((const __attribute__((address_space(1))) void*)g,
                                   (__attribute__((address_space(3))) void*)l, 16, 0, 0);
}

// ---------------- router: logits, softmax, top-2 ----------------
__global__ __launch_bounds__(64) void k_router(const float* __restrict__ hs,
                                               const float* __restrict__ gw,
                                               int* __restrict__ e01,
                                               float* __restrict__ p01) {
  int t = blockIdx.x;
  int lane = threadIdx.x;
  const float4* xv = (const float4*)(hs + (size_t)t * H_);
  float4 xr[4];
#pragma unroll
  for (int i = 0; i < 4; ++i) xr[i] = xv[lane + i * 64];
  float logit[E_];
#pragma unroll
  for (int e = 0; e < E_; ++e) {
    const float4* gv = (const float4*)(gw + (size_t)e * H_);
    float acc = 0.f;
#pragma unroll
    for (int i = 0; i < 4; ++i) {
      float4 g = gv[lane + i * 64];
      acc += xr[i].x * g.x + xr[i].y * g.y + xr[i].z * g.z + xr[i].w * g.w;
    }
#pragma unroll
    for (int off = 32; off > 0; off >>= 1) acc += __shfl_xor(acc, off);
    logit[e] = acc;
  }
  // softmax (all lanes replicate)
  float mx = logit[0];
#pragma unroll
  for (int e = 1; e < E_; ++e) mx = fmaxf(mx, logit[e]);
  float p[E_], s = 0.f;
#pragma unroll
  for (int e = 0; e < E_; ++e) { p[e] = expf(logit[e] - mx); s += p[e]; }
  float inv = 1.f / s;
  int e0 = 0;
#pragma unroll
  for (int e = 1; e < E_; ++e) if (p[e] > p[e0]) e0 = e;
  int e1 = (e0 == 0) ? 1 : 0;
#pragma unroll
  for (int e = 0; e < E_; ++e) if (e != e0 && p[e] > p[e1]) e1 = e;
  if (lane == 0) {
    e01[t * 2 + 0] = e0;
    e01[t * 2 + 1] = e1;
    p01[t * 2 + 0] = p[e0] * inv;
    p01[t * 2 + 1] = p[e1] * inv;
  }
}

// ---------------- positions: per-batch capacity cumsum ----------------
__global__ __launch_bounds__(256) void k_positions(const int* __restrict__ e01,
                                                   int* __restrict__ pos,
                                                   int* __restrict__ disp) {
  int b = blockIdx.x, tid = threadIdx.x;
  __shared__ unsigned char eid[S_ * TOPK];
  __shared__ int part[256];
  for (int i = tid; i < E_ * CAP; i += 256)
    disp[((size_t)(i / CAP) * B_ + b) * CAP + (i % CAP)] = -1;
  for (int i = tid; i < S_ * TOPK; i += 256)
    eid[i] = (unsigned char)e01[b * S_ * TOPK + i];
  __syncthreads();
  const int per = (S_ * TOPK) / 256;  // 16
  int base = tid * per;
  for (int e = 0; e < E_; ++e) {
    int cnt = 0;
    for (int j = 0; j < per; ++j) cnt += (eid[base + j] == e) ? 1 : 0;
    part[tid] = cnt;
    __syncthreads();
    for (int off = 1; off < 256; off <<= 1) {
      int v = part[tid];
      int add = (tid >= off) ? part[tid - off] : 0;
      __syncthreads();
      part[tid] = v + add;
      __syncthreads();
    }
    int run = part[tid] - cnt;  // exclusive prefix
    for (int j = 0; j < per; ++j) {
      int sl = base + j;
      if (eid[sl] == e) {
        ++run;
        int p = (run <= CAP) ? (run - 1) : -1;
        pos[b * S_ * TOPK + sl] = p;
        if (p >= 0) disp[((size_t)e * B_ + b) * CAP + p] = sl >> 1;
      }
    }
    __syncthreads();
  }
}

// ---------------- weight transpose + f32->bf16 ----------------
// in: [E][R][C] f32 ; out: [E][C][R] bf16
__global__ __launch_bounds__(256) void k_transpose(const float* __restrict__ in,
                                                   unsigned short* __restrict__ outp,
                                                   int R, int C) {
  __shared__ unsigned short ls[64][72];
  int e = blockIdx.z, tc = blockIdx.x, tr = blockIdx.y, tid = threadIdx.x;
  const float* src = in + (size_t)e * R * C + (size_t)tr * 64 * C + (size_t)tc * 64;
#pragma unroll
  for (int i = 0; i < 16; ++i) {
    int row = i * 4 + (tid >> 6), col = tid & 63;
    ls[row][col] = f2bf(src[(size_t)row * C + col]);
  }
  __syncthreads();
  unsigned short* dst = outp + (size_t)e * R * C + (size_t)tc * 64 * R + (size_t)tr * 64;
#pragma unroll
  for (int i = 0; i < 4; ++i) {
    int orow = i * 16 + (tid >> 4), oc = (tid & 15) * 4;
    us4 v = {ls[oc + 0][orow], ls[oc + 1][orow], ls[oc + 2][orow], ls[oc + 3][orow]};
    *(us4*)&dst[(size_t)orow * R + oc] = v;
  }
}

// ---------------- dispatch gather: build X_d bf16 [E][M_][H_] ----------------
__global__ __launch_bounds__(256) void k_dispatch(const float* __restrict__ hs,
                                                  const int* __restrict__ disp,
                                                  unsigned short* __restrict__ xd) {
  int slot = blockIdx.x;  // e*B*CAP + b*CAP + c
  int tid = threadIdx.x;
  int tok = disp[slot];
  int b = (slot / CAP) % B_;
  us4 v;
  if (tok >= 0) {
    const float4* src = (const float4*)(hs + ((size_t)b * S_ + tok) * H_);
    float4 f = src[tid];
    v = {f2bf(f.x), f2bf(f.y), f2bf(f.z), f2bf(f.w)};
  } else {
    v = {0, 0, 0, 0};
  }
  *(us4*)&xd[(size_t)slot * H_ + tid * 4] = v;
}

// ---------------- GEMM1: act = silu(Xd@W1) * (Xd@W3), bf16 out ----------------
// Xd: [E][M_][K=H_] ; W1t/W3t: [E][N=F_][K=H_] (row=N, K contiguous) ; Act: [E][M_][F_]
__global__ __launch_bounds__(256, 2) void k_gemm1(const unsigned short* __restrict__ Xd,
                                                  const unsigned short* __restrict__ W1t,
                                                  const unsigned short* __restrict__ W3t,
                                                  unsigned short* __restrict__ Act) {
  const int N = F_, K = H_;
  int e = blockIdx.z, tm = blockIdx.x, tn = blockIdx.y;
  const unsigned short* A  = Xd  + (size_t)e * M_ * K + (size_t)tm * 128 * K;
  const unsigned short* B1 = W1t + (size_t)e * N  * K + (size_t)tn * 128 * K;
  const unsigned short* B3 = W3t + (size_t)e * N  * K + (size_t)tn * 128 * K;
  __shared__ __align__(16) unsigned short lsA[4096], lsB1[4096], lsB3[4096];
  int tid = threadIdx.x, lane = tid & 63, wid = tid >> 6;
  int wm = wid >> 1, wn = wid & 1;
  f32x4 acc1[4][4] = {}, acc3[4][4] = {};
  int lin0 = tid, lin1 = tid + 256;
  int r0 = ((lin0 >> 6) << 4) | (lin0 & 15), kA0 = ((lin0 >> 4) & 3) * 8;
  int r1 = ((lin1 >> 6) << 4) | (lin1 & 15), kA1 = ((lin1 >> 4) & 3) * 8;
  for (int k0 = 0; k0 < K; k0 += 32) {
    gload16(A  + (size_t)r0 * K + k0 + kA0, &lsA[lin0 * 8]);
    gload16(A  + (size_t)r1 * K + k0 + kA1, &lsA[lin1 * 8]);
    gload16(B1 + (size_t)r0 * K + k0 + kA0, &lsB1[lin0 * 8]);
    gload16(B1 + (size_t)r1 * K + k0 + kA1, &lsB1[lin1 * 8]);
    gload16(B3 + (size_t)r0 * K + k0 + kA0, &lsB3[lin0 * 8]);
    gload16(B3 + (size_t)r1 * K + k0 + kA1, &lsB3[lin1 * 8]);
    __syncthreads();
    short8 af[4], bf1[4], bf3[4];
#pragma unroll
    for (int m = 0; m < 4; ++m) af[m] = *(const short8*)&lsA[(wm * 4 + m) * 512 + lane * 8];
#pragma unroll
    for (int n = 0; n < 4; ++n) {
      bf1[n] = *(const short8*)&lsB1[(wn * 4 + n) * 512 + lane * 8];
      bf3[n] = *(const short8*)&lsB3[(wn * 4 + n) * 512 + lane * 8];
    }
#pragma unroll
    for (int m = 0; m < 4; ++m)
#pragma unroll
      for (int n = 0; n < 4; ++n) {
        acc1[m][n] = __builtin_amdgcn_mfma_f32_16x16x32_bf16(af[m], bf1[n], acc1[m][n], 0, 0, 0);
        acc3[m][n] = __builtin_amdgcn_mfma_f32_16x16x32_bf16(af[m], bf3[n], acc3[m][n], 0, 0, 0);
      }
    __syncthreads();
  }
  unsigned short* out = Act + (size_t)e * M_ * N;
  int rbase = tm * 128 + wm * 64, cbase = tn * 128 + wn * 64;
#pragma unroll
  for (int m = 0; m < 4; ++m)
#pragma unroll
    for (int n = 0; n < 4; ++n) {
      int rr = rbase + m * 16 + ((lane >> 4) << 2);
      int cc = cbase + n * 16 + (lane & 15);
#pragma unroll
      for (int j = 0; j < 4; ++j) {
        float h1 = acc1[m][n][j], h3 = acc3[m][n][j];
        float sg = 1.f / (1.f + __expf(-h1));
        out[(size_t)(rr + j) * N + cc] = f2bf(h1 * sg * h3);
      }
    }
}

// ---------------- GEMM2: Oe = Act @ W2 ----------------
// Act: [E][M_][K=F_] ; W2t: [E][N=H_][K=F_] ; Oe: [E][M_][H_] bf16
__global__ __launch_bounds__(256, 2) void k_gemm2(const unsigned short* __restrict__ Act,
                                                  const unsigned short* __restrict__ W2t,
                                                  unsigned short* __restrict__ Oe) {
  const int N = H_, K = F_;
  int e = blockIdx.z, tm = blockIdx.x, tn = blockIdx.y;
  const unsigned short* A = Act + (size_t)e * M_ * K + (size_t)tm * 128 * K;
  const unsigned short* B = W2t + (size_t)e * N  * K + (size_t)tn * 128 * K;
  __shared__ __align__(16) unsigned short lsA[4096], lsB[4096];
  int tid = threadIdx.x, lane = tid & 63, wid = tid >> 6;
  int wm = wid >> 1, wn = wid & 1;
  f32x4 acc[4][4] = {};
  int lin0 = tid, lin1 = tid + 256;
  int r0 = ((lin0 >> 6) << 4) | (lin0 & 15), kA0 = ((lin0 >> 4) & 3) * 8;
  int r1 = ((lin1 >> 6) << 4) | (lin1 & 15), kA1 = ((lin1 >> 4) & 3) * 8;
  for (int k0 = 0; k0 < K; k0 += 32) {
    gload16(A + (size_t)r0 * K + k0 + kA0, &lsA[lin0 * 8]);
    gload16(A + (size_t)r1 * K + k0 + kA1, &lsA[lin1 * 8]);
    gload16(B + (size_t)r0 * K + k0 + kA0, &lsB[lin0 * 8]);
    gload16(B + (size_t)r1 * K + k0 + kA1, &lsB[lin1 * 8]);
    __syncthreads();
    short8 af[4], bf[4];
#pragma unroll
    for (int m = 0; m < 4; ++m) af[m] = *(const short8*)&lsA[(wm * 4 + m) * 512 + lane * 8];
#pragma unroll
    for (int n = 0; n < 4; ++n) bf[n] = *(const short8*)&lsB[(wn * 4 + n) * 512 + lane * 8];
#pragma unroll
    for (int m = 0; m < 4; ++m)
#pragma unroll
      for (int n = 0; n < 4; ++n)
        acc[m][n] = __builtin_amdgcn_mfma_f32_16x16x32_bf16(af[m], bf[n], acc[m][n], 0, 0, 0);
    __syncthreads();
  }
  unsigned short* out = Oe + (size_t)e * M_ * N;
  int rbase = tm * 128 + wm * 64, cbase = tn * 128 + wn * 64;
#pragma unroll
  for (int m = 0; m < 4; ++m)
#pragma unroll
    for (int n = 0; n < 4; ++n) {
      int rr = rbase + m * 16 + ((lane >> 4) << 2);
      int cc = cbase + n * 16 + (lane & 15);
#pragma unroll
      for (int j = 0; j < 4; ++j)
        out[(size_t)(rr + j) * N + cc] = f2bf(acc[m][n][j]);
    }
}

// ---------------- combine ----------------
__global__ __launch_bounds__(256) void k_combine(const unsigned short* __restrict__ Oe,
                                                 const int* __restrict__ e01,
                                                 const float* __restrict__ p01,
                                                 const int* __restrict__ pos,
                                                 float* __restrict__ outp) {
  int t = blockIdx.x;
  int b = t / S_;
  int tid = threadIdx.x;
  float4 acc = {0.f, 0.f, 0.f, 0.f};
#pragma unroll
  for (int k = 0; k < TOPK; ++k) {
    int p = pos[t * 2 + k];
    if (p >= 0) {
      int e = e01[t * 2 + k];
      float w = p01[t * 2 + k];
      size_t row = (size_t)e * M_ + (size_t)b * CAP + p;
      us4 v = *(const us4*)&Oe[row * H_ + tid * 4];
      acc.x += w * bf2f(v[0]);
      acc.y += w * bf2f(v[1]);
      acc.z += w * bf2f(v[2]);
      acc.w += w * bf2f(v[3]);
    }
  }
  *(float4*)&outp[(size_t)t * H_ + tid * 4] = acc;
}

extern "C" void kernel_launch(void* const* d_in, const int* in_sizes, int n_in,
                              void* d_out, int out_size, void* d_ws, size_t ws_size,
                              hipStream_t stream) {
  const float* hs = (const float*)d_in[0];
  const float* gw = (const float*)d_in[1];
  const float* w1 = (const float*)d_in[2];
  const float* w2 = (const float*)d_in[3];
  const float* w3 = (const float*)d_in[4];

  char* ws = (char*)d_ws;
  size_t off = 0;
  auto take = [&](size_t bytes) -> char* {
    char* p = ws + off;
    off += (bytes + 255) & ~(size_t)255;
    return p;
  };
  int*            e01  = (int*)take((size_t)NTOK * 2 * 4);
  float*          p01  = (float*)take((size_t)NTOK * 2 * 4);
  int*            pos  = (int*)take((size_t)NTOK * 2 * 4);
  int*            disp = (int*)take((size_t)E_ * B_ * CAP * 4);
  unsigned short* w1t  = (unsigned short*)take((size_t)E_ * H_ * F_ * 2);
  unsigned short* w3t  = (unsigned short*)take((size_t)E_ * H_ * F_ * 2);
  unsigned short* w2t  = (unsigned short*)take((size_t)E_ * H_ * F_ * 2);
  unsigned short* xd   = (unsigned short*)take((size_t)E_ * M_ * H_ * 2);
  unsigned short* act  = (unsigned short*)take((size_t)E_ * M_ * F_ * 2);
  unsigned short* oe   = (unsigned short*)take((size_t)E_ * M_ * H_ * 2);

  k_router<<<NTOK, 64, 0, stream>>>(hs, gw, e01, p01);
  k_positions<<<B_, 256, 0, stream>>>(e01, pos, disp);
  k_transpose<<<dim3(F_ / 64, H_ / 64, E_), 256, 0, stream>>>(w1, w1t, H_, F_);
  k_transpose<<<dim3(F_ / 64, H_ / 64, E_), 256, 0, stream>>>(w3, w3t, H_, F_);
  k_transpose<<<dim3(H_ / 64, F_ / 64, E_), 256, 0, stream>>>(w2, w2t, F_, H_);
  k_dispatch<<<E_ * B_ * CAP, 256, 0, stream>>>(hs, disp, xd);
  k_gemm1<<<dim3(M_ / 128, F_ / 128, E_), 256, 0, stream>>>(xd, w1t, w3t, act);
  k_gemm2<<<dim3(M_ / 128, H_ / 128, E_), 256, 0, stream>>>(act, w2t, oe);
  k_combine<<<NTOK, 256, 0, stream>>>(oe, e01, p01, pos, (float*)d_out);
}

// Round 2
// 634.034 us; speedup vs baseline: 1.4921x; 1.4921x over previous
//
#include <hip/hip_runtime.h>
#include <hip/hip_bf16.h>
#include <math.h>

#define B_   4
#define S_   2048
#define H_   1024
#define F_   3584
#define E_   8
#define TOPK 2
#define CAP  640
#define M_   (B_*CAP)    // 2560 rows per expert
#define NTOK (B_*S_)     // 8192

typedef __attribute__((ext_vector_type(8))) short short8;
typedef __attribute__((ext_vector_type(4))) float f32x4;
typedef __attribute__((ext_vector_type(4))) unsigned short us4;

static __device__ __forceinline__ unsigned short f2bf(float f) {
  __hip_bfloat16 h = __float2bfloat16(f);
  return *reinterpret_cast<unsigned short*>(&h);
}
static __device__ __forceinline__ float bf2f(unsigned short u) {
  unsigned int x = ((unsigned int)u) << 16;
  float f;
  __builtin_memcpy(&f, &x, 4);
  return f;
}

static __device__ __forceinline__ void gload16(const void* g, void* l) {
  __builtin_amdgcn_global_load_lds((const __attribute__((address_space(1))) void*)g,
                                   (__attribute__((address_space(3))) void*)l, 16, 0, 0);
}

#define BAR() __builtin_amdgcn_s_barrier()
#define WLG() asm volatile("s_waitcnt lgkmcnt(0)" ::: "memory")
#define WVM4() asm volatile("s_waitcnt vmcnt(4)" ::: "memory")

// ---------------- router ----------------
__global__ __launch_bounds__(64) void k_router(const float* __restrict__ hs,
                                               const float* __restrict__ gw,
                                               int* __restrict__ e01,
                                               float* __restrict__ p01) {
  int t = blockIdx.x;
  int lane = threadIdx.x;
  const float4* xv = (const float4*)(hs + (size_t)t * H_);
  float4 xr[4];
#pragma unroll
  for (int i = 0; i < 4; ++i) xr[i] = xv[lane + i * 64];
  float logit[E_];
#pragma unroll
  for (int e = 0; e < E_; ++e) {
    const float4* gv = (const float4*)(gw + (size_t)e * H_);
    float acc = 0.f;
#pragma unroll
    for (int i = 0; i < 4; ++i) {
      float4 g = gv[lane + i * 64];
      acc += xr[i].x * g.x + xr[i].y * g.y + xr[i].z * g.z + xr[i].w * g.w;
    }
#pragma unroll
    for (int off = 32; off > 0; off >>= 1) acc += __shfl_xor(acc, off);
    logit[e] = acc;
  }
  float mx = logit[0];
#pragma unroll
  for (int e = 1; e < E_; ++e) mx = fmaxf(mx, logit[e]);
  float p[E_], s = 0.f;
#pragma unroll
  for (int e = 0; e < E_; ++e) { p[e] = expf(logit[e] - mx); s += p[e]; }
  float inv = 1.f / s;
  int e0 = 0;
#pragma unroll
  for (int e = 1; e < E_; ++e) if (p[e] > p[e0]) e0 = e;
  int e1 = (e0 == 0) ? 1 : 0;
#pragma unroll
  for (int e = 0; e < E_; ++e) if (e != e0 && p[e] > p[e1]) e1 = e;
  if (lane == 0) {
    e01[t * 2 + 0] = e0;
    e01[t * 2 + 1] = e1;
    p01[t * 2 + 0] = p[e0] * inv;
    p01[t * 2 + 1] = p[e1] * inv;
  }
}

// ---------------- positions ----------------
__global__ __launch_bounds__(256) void k_positions(const int* __restrict__ e01,
                                                   int* __restrict__ pos,
                                                   int* __restrict__ disp) {
  int b = blockIdx.x, tid = threadIdx.x;
  __shared__ unsigned char eid[S_ * TOPK];
  __shared__ int part[256];
  for (int i = tid; i < E_ * CAP; i += 256)
    disp[((size_t)(i / CAP) * B_ + b) * CAP + (i % CAP)] = -1;
  for (int i = tid; i < S_ * TOPK; i += 256)
    eid[i] = (unsigned char)e01[b * S_ * TOPK + i];
  __syncthreads();
  const int per = (S_ * TOPK) / 256;  // 16
  int base = tid * per;
  for (int e = 0; e < E_; ++e) {
    int cnt = 0;
    for (int j = 0; j < per; ++j) cnt += (eid[base + j] == e) ? 1 : 0;
    part[tid] = cnt;
    __syncthreads();
    for (int off = 1; off < 256; off <<= 1) {
      int v = part[tid];
      int add = (tid >= off) ? part[tid - off] : 0;
      __syncthreads();
      part[tid] = v + add;
      __syncthreads();
    }
    int run = part[tid] - cnt;
    for (int j = 0; j < per; ++j) {
      int sl = base + j;
      if (eid[sl] == e) {
        ++run;
        int p = (run <= CAP) ? (run - 1) : -1;
        pos[b * S_ * TOPK + sl] = p;
        if (p >= 0) disp[((size_t)e * B_ + b) * CAP + p] = sl >> 1;
      }
    }
    __syncthreads();
  }
}

// ---------------- weight transpose + f32->bf16 (optional 16-row interleave) ----------------
// in: [E][R][C] f32 ; out row ri gets source col gr; ileave: ri = (gr&~15)*2 + (gr&15) + half*16
__global__ __launch_bounds__(256) void k_transpose(const float* __restrict__ in,
                                                   unsigned short* __restrict__ outp,
                                                   int R, int C, int ileave, int half,
                                                   size_t ostride_e) {
  __shared__ unsigned short ls[64][72];
  int e = blockIdx.z, tc = blockIdx.x, tr = blockIdx.y, tid = threadIdx.x;
  const float* src = in + (size_t)e * R * C + (size_t)tr * 64 * C + (size_t)tc * 64;
#pragma unroll
  for (int i = 0; i < 16; ++i) {
    int row = i * 4 + (tid >> 6), col = tid & 63;
    ls[row][col] = f2bf(src[(size_t)row * C + col]);
  }
  __syncthreads();
  unsigned short* dbase = outp + (size_t)e * ostride_e;
#pragma unroll
  for (int i = 0; i < 4; ++i) {
    int orow = i * 16 + (tid >> 4), oc = (tid & 15) * 4;
    int gr = tc * 64 + orow;
    int ri = ileave ? ((gr & ~15) * 2 + (gr & 15) + half * 16) : gr;
    us4 v = {ls[oc + 0][orow], ls[oc + 1][orow], ls[oc + 2][orow], ls[oc + 3][orow]};
    *(us4*)&dbase[(size_t)ri * R + tr * 64 + oc] = v;
  }
}

// ---------------- dispatch gather ----------------
__global__ __launch_bounds__(256) void k_dispatch(const float* __restrict__ hs,
                                                  const int* __restrict__ disp,
                                                  unsigned short* __restrict__ xd) {
  int slot = blockIdx.x;
  int tid = threadIdx.x;
  int tok = disp[slot];
  int b = (slot / CAP) % B_;
  us4 v;
  if (tok >= 0) {
    const float4* src = (const float4*)(hs + ((size_t)b * S_ + tok) * H_);
    float4 f = src[tid];
    v = {f2bf(f.x), f2bf(f.y), f2bf(f.z), f2bf(f.w)};
  } else {
    v = {0, 0, 0, 0};
  }
  *(us4*)&xd[(size_t)slot * H_ + tid * 4] = v;
}

// ---------------- 256x256 8-phase GEMM (T2+T3+T4+T5) ----------------
// A: [E][M_][KTOT] bf16 ; B: [E][NTOTB][KTOT] bf16 (N-major, K contiguous)
// SWIGLU: B rows interleave w1/w3 at 16-granularity; out = [E][M_][NTOTB/2] bf16
// else:   out = [E][M_][NTOTB] bf16
// LDS regions 16KiB each: idx = (dreg*4 + opsel + h)*8192 ushorts; opsel A=0,B=2
// Read swizzle: slot s = (lane>>4) ^ ((row>>1)&3); write side pre-swizzles global src.
#define STAGE(src, opsel, dreg, t, h) do {                                   \
    int _ro = ((dreg)*4 + (opsel) + (h)) * 8192 + tid * 8;                   \
    const unsigned short* _p = (src) + (size_t)(t) * 64 + (h) * 32;          \
    gload16(_p, &lds[_ro]);                                                  \
    gload16(_p + (size_t)128 * KTOT, &lds[_ro + 4096]);                      \
  } while (0)

#define RD_A(d, h) {                                                         \
    const unsigned short* _pa = &lds[((d)*4 + (h)) * 8192 + aoff];           \
    _Pragma("unroll") for (int m = 0; m < 8; ++m)                            \
      a[m] = *(const short8*)&_pa[m * 512];                                  \
  }
#define RD_B(d, h, nh) {                                                     \
    const unsigned short* _pb = &lds[((d)*4 + 2 + (h)) * 8192 + boff];       \
    b0 = *(const short8*)&_pb[(nh) * 1024];                                  \
    b1 = *(const short8*)&_pb[(nh) * 1024 + 512];                            \
  }
#define MFMA8(nh) {                                                          \
    __builtin_amdgcn_s_setprio(1);                                           \
    _Pragma("unroll") for (int m = 0; m < 8; ++m) {                          \
      acc[m][(nh)*2]   = __builtin_amdgcn_mfma_f32_16x16x32_bf16(a[m], b0, acc[m][(nh)*2],   0, 0, 0); \
      acc[m][(nh)*2+1] = __builtin_amdgcn_mfma_f32_16x16x32_bf16(a[m], b1, acc[m][(nh)*2+1], 0, 0, 0); \
    }                                                                        \
    __builtin_amdgcn_s_setprio(0);                                           \
  }

template <int KTOT, bool SWIGLU, int MT, int NTN, int NTOTB>
__global__ __launch_bounds__(512, 2) void k_gemm256(const unsigned short* __restrict__ Aall,
                                                    const unsigned short* __restrict__ Ball,
                                                    unsigned short* __restrict__ Cout) {
  constexpr int NT = KTOT / 64;
  constexpr int NI = NT / 2;
  __shared__ __align__(16) unsigned short lds[65536];  // 128 KiB

  const int nwg = MT * NTN * E_;
  int lid = blockIdx.x;
  int sw = (lid & 7) * (nwg >> 3) + (lid >> 3);  // XCD swizzle (nwg%8==0)
  int e = sw / (MT * NTN);
  int rem = sw - e * (MT * NTN);
  int tn = rem / MT, tm = rem - tn * MT;

  int tid = threadIdx.x, li = tid & 63, wid = tid >> 6;
  int wm = wid >> 2, wn = wid & 3;

  // stage-side per-thread source (inverse-swizzled global address, rule #21)
  int rS = tid >> 2;
  int gS = (tid & 3) ^ ((tid >> 3) & 3);
  const unsigned short* srcA = Aall + ((size_t)e * M_ + (size_t)tm * 256 + rS) * KTOT + gS * 8;
  const unsigned short* srcB = Ball + ((size_t)e * NTOTB + (size_t)tn * 256 + rS) * KTOT + gS * 8;

  // read-side swizzled offsets (ushort units); frag m/n adds m*512
  int sA = (li >> 4) ^ ((li >> 1) & 3);
  int aoff = (wm * 128 + (li & 15)) * 32 + sA * 8;
  int boff = (wn * 64 + (li & 15)) * 32 + sA * 8;

  f32x4 acc[8][4] = {};
  short8 a[8], b0, b1;

  // prologue: tile0 all 4 halves + tile1 kk0 halves
  STAGE(srcA, 0, 0, 0, 0);
  STAGE(srcB, 2, 0, 0, 0);
  STAGE(srcA, 0, 0, 0, 1);
  STAGE(srcB, 2, 0, 0, 1);
  STAGE(srcA, 0, 1, 1, 0);
  STAGE(srcB, 2, 1, 1, 0);
  WVM4();
  BAR();

#pragma unroll 1
  for (int i = 0; i < NI; ++i) {
    int t1 = 2 * i + 1;                                  // never exceeds NT-1
    int t2 = (2 * i + 2 < NT) ? 2 * i + 2 : NT - 1;      // clamped src, dead region when clamped
    int t3 = (2 * i + 3 < NT) ? 2 * i + 3 : NT - 1;
    // P1: tile 2i, kk0, n01
    RD_A(0, 0); RD_B(0, 0, 0); STAGE(srcA, 0, 1, t1, 1);
    BAR(); WLG(); MFMA8(0); BAR();
    // P2: tile 2i, kk0, n23
    RD_B(0, 0, 1); STAGE(srcB, 2, 1, t1, 1);
    BAR(); WLG(); MFMA8(1); BAR();
    // P3: tile 2i, kk1, n01
    RD_A(0, 1); RD_B(0, 1, 0); STAGE(srcA, 0, 0, t2, 0);
    BAR(); WLG(); MFMA8(0); BAR();
    // P4: tile 2i, kk1, n23  + vmcnt gate for tile 2i+1
    RD_B(0, 1, 1); STAGE(srcB, 2, 0, t2, 0); WVM4();
    BAR(); WLG(); MFMA8(1); BAR();
    // P5: tile 2i+1, kk0, n01
    RD_A(1, 0); RD_B(1, 0, 0); STAGE(srcA, 0, 0, t2, 1);
    BAR(); WLG(); MFMA8(0); BAR();
    // P6
    RD_B(1, 0, 1); STAGE(srcB, 2, 0, t2, 1);
    BAR(); WLG(); MFMA8(1); BAR();
    // P7
    RD_A(1, 1); RD_B(1, 1, 0); STAGE(srcA, 0, 1, t3, 0);
    BAR(); WLG(); MFMA8(0); BAR();
    // P8 + vmcnt gate for tile 2i+2
    RD_B(1, 1, 1); STAGE(srcB, 2, 1, t3, 0); WVM4();
    BAR(); WLG(); MFMA8(1); BAR();
  }

  // epilogue
  int r0 = tm * 256 + wm * 128 + ((li >> 4) << 2);
  if constexpr (SWIGLU) {
    unsigned short* out = Cout + (size_t)e * M_ * F_;
#pragma unroll
    for (int m = 0; m < 8; ++m)
#pragma unroll
      for (int u = 0; u < 2; ++u) {
        int col = (tn * 8 + wn * 2 + u) * 16 + (li & 15);
#pragma unroll
        for (int j = 0; j < 4; ++j) {
          float h1 = acc[m][2 * u][j], h3 = acc[m][2 * u + 1][j];
          float sg = 1.f / (1.f + __expf(-h1));
          out[(size_t)(r0 + m * 16 + j) * F_ + col] = f2bf(h1 * sg * h3);
        }
      }
  } else {
    unsigned short* out = Cout + (size_t)e * M_ * NTOTB;
#pragma unroll
    for (int m = 0; m < 8; ++m)
#pragma unroll
      for (int n = 0; n < 4; ++n) {
        int col = tn * 256 + wn * 64 + n * 16 + (li & 15);
#pragma unroll
        for (int j = 0; j < 4; ++j)
          out[(size_t)(r0 + m * 16 + j) * NTOTB + col] = f2bf(acc[m][n][j]);
      }
  }
}

// ---------------- combine ----------------
__global__ __launch_bounds__(256) void k_combine(const unsigned short* __restrict__ Oe,
                                                 const int* __restrict__ e01,
                                                 const float* __restrict__ p01,
                                                 const int* __restrict__ pos,
                                                 float* __restrict__ outp) {
  int t = blockIdx.x;
  int b = t / S_;
  int tid = threadIdx.x;
  float4 acc = {0.f, 0.f, 0.f, 0.f};
#pragma unroll
  for (int k = 0; k < TOPK; ++k) {
    int p = pos[t * 2 + k];
    if (p >= 0) {
      int e = e01[t * 2 + k];
      float w = p01[t * 2 + k];
      size_t row = (size_t)e * M_ + (size_t)b * CAP + p;
      us4 v = *(const us4*)&Oe[row * H_ + tid * 4];
      acc.x += w * bf2f(v[0]);
      acc.y += w * bf2f(v[1]);
      acc.z += w * bf2f(v[2]);
      acc.w += w * bf2f(v[3]);
    }
  }
  *(float4*)&outp[(size_t)t * H_ + tid * 4] = acc;
}

extern "C" void kernel_launch(void* const* d_in, const int* in_sizes, int n_in,
                              void* d_out, int out_size, void* d_ws, size_t ws_size,
                              hipStream_t stream) {
  const float* hs = (const float*)d_in[0];
  const float* gw = (const float*)d_in[1];
  const float* w1 = (const float*)d_in[2];
  const float* w2 = (const float*)d_in[3];
  const float* w3 = (const float*)d_in[4];

  char* ws = (char*)d_ws;
  size_t off = 0;
  auto take = [&](size_t bytes) -> char* {
    char* p = ws + off;
    off += (bytes + 255) & ~(size_t)255;
    return p;
  };
  int*            e01  = (int*)take((size_t)NTOK * 2 * 4);
  float*          p01  = (float*)take((size_t)NTOK * 2 * 4);
  int*            pos  = (int*)take((size_t)NTOK * 2 * 4);
  int*            disp = (int*)take((size_t)E_ * B_ * CAP * 4);
  unsigned short* w13t = (unsigned short*)take((size_t)E_ * 2 * F_ * H_ * 2);
  unsigned short* w2t  = (unsigned short*)take((size_t)E_ * H_ * F_ * 2);
  unsigned short* xd   = (unsigned short*)take((size_t)E_ * M_ * H_ * 2);
  unsigned short* act  = (unsigned short*)take((size_t)E_ * M_ * F_ * 2);
  unsigned short* oe   = (unsigned short*)take((size_t)E_ * M_ * H_ * 2);

  k_router<<<NTOK, 64, 0, stream>>>(hs, gw, e01, p01);
  k_positions<<<B_, 256, 0, stream>>>(e01, pos, disp);
  // w1 -> even 16-row blocks of W13t, w3 -> odd 16-row blocks
  k_transpose<<<dim3(F_ / 64, H_ / 64, E_), 256, 0, stream>>>(w1, w13t, H_, F_, 1, 0, (size_t)2 * F_ * H_);
  k_transpose<<<dim3(F_ / 64, H_ / 64, E_), 256, 0, stream>>>(w3, w13t, H_, F_, 1, 1, (size_t)2 * F_ * H_);
  k_transpose<<<dim3(H_ / 64, F_ / 64, E_), 256, 0, stream>>>(w2, w2t, F_, H_, 0, 0, (size_t)H_ * F_);
  k_dispatch<<<E_ * B_ * CAP, 256, 0, stream>>>(hs, disp, xd);
  // GEMM1: [M_ x 2F] over K=H, SwiGLU epilogue -> act [E][M_][F_]
  k_gemm256<H_, true, M_ / 256, (2 * F_) / 256, 2 * F_><<<(M_ / 256) * ((2 * F_) / 256) * E_, 512, 0, stream>>>(xd, w13t, act);
  // GEMM2: [M_ x H] over K=F
  k_gemm256<F_, false, M_ / 256, H_ / 256, H_><<<(M_ / 256) * (H_ / 256) * E_, 512, 0, stream>>>(act, w2t, oe);
  k_combine<<<NTOK, 256, 0, stream>>>(oe, e01, p01, pos, (float*)d_out);
}